// Round 11
// baseline (1380.611 us; speedup 1.0000x reference)
//
#include <hip/hip_runtime.h>
#include <hip/hip_bf16.h>
#include <math.h>

typedef unsigned short u16;
typedef unsigned int u32;
typedef __attribute__((ext_vector_type(4))) float f32x4;
typedef __attribute__((ext_vector_type(8))) short bf16x8;

#define DEV static __device__ __forceinline__

DEV u16 f2bf(float f) {
  __hip_bfloat16 h = __float2bfloat16(f);
  union { __hip_bfloat16 h; u16 u; } c; c.h = h; return c.u;
}

DEV float fast_gelu(float v) {
  float u = v * (1.5957691216f + 0.0713548162f * v * v);
  return v * __builtin_amdgcn_rcpf(1.f + __expf(-u));
}

DEV void gload16(const void* g, void* l) {
  __builtin_amdgcn_global_load_lds((const __attribute__((address_space(1))) u32*)g,
                                   (__attribute__((address_space(3))) u32*)l, 16, 0, 0);
}

// ------- weight transpose: fp32 [R][C] -> bf16 [C][Rp]; gridDim.z = layer -------
__global__ void transpose_w(const float* __restrict__ src, u16* __restrict__ dst,
                            int R, int C, int Rp, size_t sstride, size_t dstride) {
  src += (size_t)blockIdx.z * sstride;
  dst += (size_t)blockIdx.z * dstride;
  __shared__ float tile[32][33];
  int tx = threadIdx.x, ty = threadIdx.y;
  int c0 = blockIdx.x * 32, r0 = blockIdx.y * 32;
  #pragma unroll
  for (int j = 0; j < 4; j++) {
    int r = r0 + ty + j * 8, c = c0 + tx;
    tile[ty + j * 8][tx] = (r < R && c < C) ? src[(size_t)r * C + c] : 0.f;
  }
  __syncthreads();
  #pragma unroll
  for (int j = 0; j < 4; j++) {
    int cc = c0 + ty + j * 8;
    int rr = r0 + tx;
    if (cc < C && rr < Rp) dst[(size_t)cc * Rp + rr] = f2bf(tile[tx][ty + j * 8]);
  }
}

// ---------------- concat [z|a|task|0pad] -> bf16 [8192][704] ----------------
__global__ void concat_k(const float* __restrict__ z, const float* __restrict__ a,
                         const float* __restrict__ te, u16* __restrict__ A) {
  const int total = 8192 * 704;
  for (int idx = blockIdx.x * 256 + threadIdx.x; idx < total; idx += gridDim.x * 256) {
    int m = idx / 704;
    int j = idx - m * 704;
    float v = 0.f;
    if (j < 512) v = z[(size_t)m * 512 + j];
    else if (j < 576) v = a[(size_t)m * 64 + (j - 512)];
    else if (j < 672) v = te[(size_t)m * 96 + (j - 576)];
    A[idx] = f2bf(v);
  }
}

// ---------------- LayerNorm: fp32 [M][1024] -> bf16 [M][1024], one wave per row ----
__global__ __launch_bounds__(256) void ln_k(const float* __restrict__ x,
                                            const float* __restrict__ w,
                                            const float* __restrict__ b,
                                            u16* __restrict__ h) {
  int row = blockIdx.x * 4 + (threadIdx.x >> 6);
  int lane = threadIdx.x & 63;
  const float4* xr = (const float4*)(x + (size_t)row * 1024);
  float4 v[4]; float s = 0.f, sq = 0.f;
  #pragma unroll
  for (int i = 0; i < 4; i++) {
    v[i] = xr[lane + i * 64];
    s += v[i].x + v[i].y + v[i].z + v[i].w;
    sq += v[i].x * v[i].x + v[i].y * v[i].y + v[i].z * v[i].z + v[i].w * v[i].w;
  }
  #pragma unroll
  for (int off = 32; off >= 1; off >>= 1) { s += __shfl_xor(s, off); sq += __shfl_xor(sq, off); }
  float mean = s * (1.f / 1024.f);
  float var = sq * (1.f / 1024.f) - mean * mean;
  float rstd = rsqrtf(var + 1e-5f);
  const float4* wv = (const float4*)w;
  const float4* bv = (const float4*)b;
  u32* hr = (u32*)(h + (size_t)row * 1024);
  #pragma unroll
  for (int i = 0; i < 4; i++) {
    int idx = lane + i * 64;
    float4 wi = wv[idx], bi = bv[idx];
    float o0 = (v[i].x - mean) * rstd * wi.x + bi.x;
    float o1 = (v[i].y - mean) * rstd * wi.y + bi.y;
    float o2 = (v[i].z - mean) * rstd * wi.z + bi.z;
    float o3 = (v[i].w - mean) * rstd * wi.w + bi.w;
    hr[idx * 2]     = (u32)f2bf(o0) | ((u32)f2bf(o1) << 16);
    hr[idx * 2 + 1] = (u32)f2bf(o2) | ((u32)f2bf(o3) << 16);
  }
}

// ---------------- legacy GEMM (used for K=704 input proj) ----------------
template <int FM, int EPI>
__global__ __launch_bounds__(512, 2) void gemm8(
    const u16* __restrict__ A, const u16* __restrict__ BT,
    float* __restrict__ outF, u16* __restrict__ outH,
    const float* __restrict__ bias, const float* __restrict__ res,
    const float* __restrict__ pos, int M, int N, int K, int gx) {
  constexpr int BM = FM * 32;
  constexpr int ABYTES = BM * 64;
  constexpr int BBYTES = 256 * 64;
  constexpr int SLICE = ABYTES + BBYTES;
  constexpr int LA = ABYTES / 8192;
  constexpr int LB = 2;
  __shared__ char lds[4 * SLICE];

  const int tid = threadIdx.x, lane = tid & 63, w = tid >> 6;
  const int wr = w >> 2, wc = w & 3;

  const int nwg = gridDim.x, orig = blockIdx.x;
  const int q = nwg >> 3, r = nwg & 7;
  const int xcd = orig & 7, loc = orig >> 3;
  const int sid = (xcd < r ? xcd * (q + 1) : r * (q + 1) + (xcd - r) * q) + loc;
  const int m0 = (sid / gx) * BM, n0 = (sid % gx) * 256;

  const char* Ag = (const char*)(A + (size_t)m0 * K);
  const char* Bg = (const char*)(BT + (size_t)n0 * K);
  const int Krow = K * 2;

  int aoff[LA], boff[LB];
  #pragma unroll
  for (int l = 0; l < LA; l++) {
    int c = l * 512 + tid, rw = c >> 2, g = (c & 3) ^ ((rw >> 1) & 3);
    aoff[l] = rw * Krow + g * 16;
  }
  #pragma unroll
  for (int l = 0; l < LB; l++) {
    int c = l * 512 + tid, rw = c >> 2, g = (c & 3) ^ ((rw >> 1) & 3);
    boff[l] = rw * Krow + g * 16;
  }
  const int ra = wr * (FM * 16) + (lane & 15);
  const int aRd = ra * 64 + (((lane >> 4) ^ ((ra >> 1) & 3)) << 4);
  const int rb = wc * 64 + (lane & 15);
  const int bRd = rb * 64 + (((lane >> 4) ^ ((rb >> 1) & 3)) << 4);

  f32x4 zero4 = {0.f, 0.f, 0.f, 0.f};
  f32x4 acc[FM][4];
  #pragma unroll
  for (int m = 0; m < FM; m++)
    #pragma unroll
    for (int n = 0; n < 4; n++) acc[m][n] = zero4;

  auto stageA = [&](int s) {
    char* Ad = lds + (s & 3) * SLICE;
    const char* src = Ag + (size_t)s * 64;
    #pragma unroll
    for (int l = 0; l < LA; l++)
      gload16(src + aoff[l], Ad + (l * 512 + w * 64) * 16);
  };
  auto stageB = [&](int s) {
    char* Bd = lds + (s & 3) * SLICE + ABYTES;
    const char* src = Bg + (size_t)s * 64;
    #pragma unroll
    for (int l = 0; l < LB; l++)
      gload16(src + boff[l], Bd + (l * 512 + w * 64) * 16);
  };

  const int NS = K >> 5;
  stageA(0); stageB(0); stageA(1); stageB(1);
  asm volatile("s_waitcnt vmcnt(3)" ::: "memory");
  __builtin_amdgcn_s_barrier();

  #pragma unroll 1
  for (int s = 0; s < NS; s++) {
    char* Ar = lds + (s & 3) * SLICE;
    char* Br = Ar + ABYTES;
    const bool pre = (s + 2 < NS);
    bf16x8 bfr[4], af[4];
    #pragma unroll
    for (int n = 0; n < 4; n++) bfr[n] = *(const bf16x8*)(Br + bRd + n * 1024);
    #pragma unroll
    for (int m = 0; m < 4; m++) af[m] = *(const bf16x8*)(Ar + aRd + m * 1024);
    if (pre) { stageA(s + 2); stageB(s + 2); }
    __builtin_amdgcn_sched_barrier(0);
    __builtin_amdgcn_s_barrier();
    asm volatile("s_waitcnt lgkmcnt(0)" ::: "memory");
    __builtin_amdgcn_sched_barrier(0);
    __builtin_amdgcn_s_setprio(1);
    #pragma unroll
    for (int m = 0; m < 4; m++)
      #pragma unroll
      for (int n = 0; n < 4; n++)
        acc[m][n] = __builtin_amdgcn_mfma_f32_16x16x32_bf16(af[m], bfr[n], acc[m][n], 0, 0, 0);
    __builtin_amdgcn_s_setprio(0);
    __builtin_amdgcn_sched_barrier(0);
    if (pre) asm volatile("s_waitcnt vmcnt(3)" ::: "memory");
    else     asm volatile("s_waitcnt vmcnt(0)" ::: "memory");
    __builtin_amdgcn_s_barrier();
  }

  #pragma unroll
  for (int m = 0; m < FM; m++) {
    #pragma unroll
    for (int i = 0; i < 4; i++) {
      int gm = m0 + wr * (FM * 16) + m * 16 + ((lane >> 4) << 2) + i;
      #pragma unroll
      for (int n = 0; n < 4; n++) {
        int gn = n0 + wc * 64 + n * 16 + (lane & 15);
        float v = acc[m][n][i];
        if (EPI & 1) v += bias[gn];
        if (EPI & 2) v += pos[(size_t)(gm & 511) * N + gn];
        if (EPI & 4) v += res[(size_t)gm * N + gn];
        if (EPI & 8) v = fast_gelu(v);
        if (EPI & 16) outH[(size_t)gm * N + gn] = f2bf(v);
        else outF[(size_t)gm * N + gn] = v;
      }
    }
  }
}

// ======= gemmD: BM=128 x BN=256, BK=32, 3-slice rotation, 72KB LDS, 2 WGs/CU ======
// Slice = [A 8KB][B0 8KB][B1 8KB] (regions [128 rows][32 K] bf16, rows 64B,
// 4x16B slots XOR (row&3)). Iter s: reads slice s%3; stage s+2 -> (s+2)%3
// (WAR safe: its readers lgkm-drained in iter s-1 before that barrier);
// vmcnt(3) at END (publication before barrier; slice s+1 retired, s+2 stays
// in flight — never drains to 0). VGPR<=128 so 2 WGs (16 waves) co-reside.
template <int EPI>
__global__ __launch_bounds__(512, 4) void gemmD(
    const u16* __restrict__ A, const u16* __restrict__ BT,
    float* __restrict__ outF, u16* __restrict__ outH,
    const float* __restrict__ bias, const float* __restrict__ res,
    const float* __restrict__ pos, int M, int N, int K, int gx) {
  constexpr int SLICE = 24576;
  __shared__ char lds[3 * SLICE];

  const int tid = threadIdx.x, lane = tid & 63, w = tid >> 6;
  const int wr = w >> 2, wc = w & 3;
  const int ln = lane & 15, g = lane >> 4;

  const int nwg = gridDim.x, orig = blockIdx.x;
  const int q = nwg >> 3, r = nwg & 7;
  const int xcd = orig & 7, loc = orig >> 3;
  const int sid = (xcd < r ? xcd * (q + 1) : r * (q + 1) + (xcd - r) * q) + loc;
  const int m0 = (sid / gx) * 128, n0 = (sid % gx) * 256;

  const char* Ag = (const char*)(A + (size_t)m0 * K);
  const char* Bg = (const char*)(BT + (size_t)n0 * K);
  const int K2 = K * 2;
  const int NS = K >> 5, NSm1 = NS - 1;

  // read offsets (region-local): row rr, 64B rows, slot = g ^ (rr&3) = g ^ (ln&3)
  const int slotR = (g ^ (ln & 3)) << 4;
  int aby[4], bby[4];
  #pragma unroll
  for (int m = 0; m < 4; m++) aby[m] = (wr * 64 + m * 16 + ln) * 64 + slotR;
  #pragma unroll
  for (int n = 0; n < 4; n++)
    bby[n] = 8192 + (wc >> 1) * 8192 + ((wc & 1) * 64 + n * 16 + ln) * 64 + slotR;

  // staging offsets (pre-swizzled source, lane-linear dest)
  const int arw = tid >> 2, asl = tid & 3;
  const int aoff = arw * K2 + ((asl ^ (arw & 3)) << 4);
  const int brw1 = 128 + (tid >> 2);
  const int boff0 = aoff;  // B rows 0..127 same formula
  const int boff1 = brw1 * K2 + ((asl ^ (brw1 & 3)) << 4);

  auto stage = [&](int sl3, int tau) {
    int tt = tau < NS ? tau : NSm1;
    char* base = lds + sl3 * SLICE;
    const char* sa = Ag + (size_t)tt * 64;
    const char* sb = Bg + (size_t)tt * 64;
    gload16(sa + aoff, base + tid * 16);
    gload16(sb + boff0, base + 8192 + tid * 16);
    gload16(sb + boff1, base + 8192 + (512 + tid) * 16);
  };

  f32x4 zero4 = {0.f, 0.f, 0.f, 0.f};
  f32x4 acc[4][4];
  #pragma unroll
  for (int m = 0; m < 4; m++)
    #pragma unroll
    for (int n = 0; n < 4; n++) acc[m][n] = zero4;

  bf16x8 afr[4], bfr[4];

  // prologue: slices 0,1 (6 loads); vmcnt(3) -> slice0 landed, publish
  stage(0, 0); stage(1, 1);
  asm volatile("s_waitcnt vmcnt(3)" ::: "memory");
  __builtin_amdgcn_s_barrier();

  int s0 = 0, s1 = 1, s2 = 2;
  #pragma unroll 1
  for (int s = 0; s < NS; s++) {
    const char* base = lds + s0 * SLICE;
    stage(s2, s + 2);
    #pragma unroll
    for (int n = 0; n < 4; n++) bfr[n] = *(const bf16x8*)(base + bby[n]);
    #pragma unroll
    for (int m = 0; m < 4; m++) afr[m] = *(const bf16x8*)(base + aby[m]);
    __builtin_amdgcn_sched_barrier(0);
    asm volatile("s_waitcnt lgkmcnt(0)" ::: "memory");
    __builtin_amdgcn_sched_barrier(0);
    __builtin_amdgcn_s_setprio(1);
    #pragma unroll
    for (int m = 0; m < 4; m++)
      #pragma unroll
      for (int n = 0; n < 4; n++)
        acc[m][n] = __builtin_amdgcn_mfma_f32_16x16x32_bf16(afr[m], bfr[n], acc[m][n], 0, 0, 0);
    __builtin_amdgcn_s_setprio(0);
    __builtin_amdgcn_sched_barrier(0);
    asm volatile("s_waitcnt vmcnt(3)" ::: "memory");  // slice s+1 published
    __builtin_amdgcn_s_barrier();
    int t = s0; s0 = s1; s1 = s2; s2 = t;
  }

  // epilogue
  #pragma unroll
  for (int m = 0; m < 4; m++) {
    #pragma unroll
    for (int i = 0; i < 4; i++) {
      int gm = m0 + wr * 64 + m * 16 + (g << 2) + i;
      #pragma unroll
      for (int n = 0; n < 4; n++) {
        int gn = n0 + wc * 64 + n * 16 + ln;
        float v = acc[m][n][i];
        if (EPI & 1) v += bias[gn];
        if (EPI & 2) v += pos[(size_t)(gm & 511) * N + gn];
        if (EPI & 4) v += res[(size_t)gm * N + gn];
        if (EPI & 8) v = fast_gelu(v);
        if (EPI & 16) outH[(size_t)gm * N + gn] = f2bf(v);
        else outF[(size_t)gm * N + gn] = v;
      }
    }
  }
}

// -------- fused causal attention, one WG per (b,h), 8 waves, KVBLK=64 --------
__global__ __launch_bounds__(512) void attn_k(const u16* __restrict__ qkv,
                                              u16* __restrict__ o) {
  __shared__ u16 Ks[512 * 64];
  __shared__ u16 Vt[64 * 512];
  __shared__ u16 Ps[8 * 1024];
  const int tid = threadIdx.x, lane = tid & 63, w = tid >> 6;
  const int b = blockIdx.x >> 4, h = blockIdx.x & 15;
  const u16* base = qkv + (size_t)b * 512 * 3072 + h * 64;
  const int ln = lane & 15, g = lane >> 4;

  #pragma unroll
  for (int it = 0; it < 8; it++) {
    int chunk = it * 512 + tid;
    int row = chunk >> 3;
    int ib = (chunk & 7) * 16;
    int lb = ib ^ ((row & 7) << 4);
    gload16((const char*)(base + 1024 + (size_t)row * 3072) + lb,
            (char*)Ks + (it * 512 + w * 64) * 16);
  }
  {
    const u16* vrow = base + 2048 + (size_t)tid * 3072;
    #pragma unroll
    for (int c = 0; c < 8; c++) {
      uint4 u = *(const uint4*)(vrow + c * 8);
      u32 vals[4] = {u.x, u.y, u.z, u.w};
      #pragma unroll
      for (int pc = 0; pc < 4; pc++) {
        int d0 = c * 8 + pc * 2;
        size_t by0 = ((size_t)d0 * 1024 + tid * 2) ^ (size_t)((d0 & 7) << 4);
        size_t by1 = ((size_t)(d0 + 1) * 1024 + tid * 2) ^ (size_t)(((d0 + 1) & 7) << 4);
        *(u16*)((char*)Vt + by0) = (u16)(vals[pc] & 0xffff);
        *(u16*)((char*)Vt + by1) = (u16)(vals[pc] >> 16);
      }
    }
  }
  __syncthreads();

  const int qts[4] = {w, 15 - w, 16 + w, 31 - w};
  #pragma unroll
  for (int qi = 0; qi < 4; qi++) {
    const int qt = qts[qi];
    const int q0 = qt * 16;
    const int qcol = q0 + ln;
    const u16* qrow = base + (size_t)(q0 + ln) * 3072 + (g << 3);
    bf16x8 qf0 = *(const bf16x8*)qrow;
    bf16x8 qf1 = *(const bf16x8*)(qrow + 32);
    f32x4 zero4 = {0.f, 0.f, 0.f, 0.f};
    f32x4 oA[4] = {zero4, zero4, zero4, zero4};
    float mrun = -INFINITY, lrun = 0.f;
    const int nch = (qt >> 2) + 1;
    for (int ch = 0; ch < nch; ch++) {
      const int kb = ch * 64;
      f32x4 st[4];
      #pragma unroll
      for (int s = 0; s < 4; s++) {
        st[s] = zero4;
        int krow = kb + s * 16 + ln;
        int byc = krow * 128 + (g << 4);
        int sw = (krow & 7) << 4;
        bf16x8 ka  = *(const bf16x8*)((const char*)Ks + (byc ^ sw));
        bf16x8 kb2 = *(const bf16x8*)((const char*)Ks + ((byc + 64) ^ sw));
        st[s] = __builtin_amdgcn_mfma_f32_16x16x32_bf16(ka, qf0, st[s], 0, 0, 0);
        st[s] = __builtin_amdgcn_mfma_f32_16x16x32_bf16(kb2, qf1, st[s], 0, 0, 0);
      }
      float sv[16]; float cmax = -INFINITY;
      #pragma unroll
      for (int s = 0; s < 4; s++) {
        #pragma unroll
        for (int i = 0; i < 4; i++) {
          int key0 = kb + s * 16 + (g << 2) + i;
          float v = st[s][i] * 0.125f;
          if (key0 > qcol) v = -INFINITY;
          sv[s * 4 + i] = v;
          cmax = fmaxf(cmax, v);
        }
      }
      cmax = fmaxf(cmax, __shfl_xor(cmax, 16));
      cmax = fmaxf(cmax, __shfl_xor(cmax, 32));
      float mnew = fmaxf(mrun, cmax);
      float corr = __expf(mrun - mnew);
      float pp[16]; float psum = 0.f;
      #pragma unroll
      for (int i = 0; i < 16; i++) { pp[i] = __expf(sv[i] - mnew); psum += pp[i]; }
      psum += __shfl_xor(psum, 16);
      psum += __shfl_xor(psum, 32);
      lrun = lrun * corr + psum;
      mrun = mnew;
      {
        int sw2 = (ln & 3) << 4;
        #pragma unroll
        for (int hh = 0; hh < 2; hh++) {
          int pbase = w * 2048 + hh * 1024 + ln * 64;
          uint2 t0, t1;
          t0.x = (u32)f2bf(pp[8 * hh + 0]) | ((u32)f2bf(pp[8 * hh + 1]) << 16);
          t0.y = (u32)f2bf(pp[8 * hh + 2]) | ((u32)f2bf(pp[8 * hh + 3]) << 16);
          t1.x = (u32)f2bf(pp[8 * hh + 4]) | ((u32)f2bf(pp[8 * hh + 5]) << 16);
          t1.y = (u32)f2bf(pp[8 * hh + 6]) | ((u32)f2bf(pp[8 * hh + 7]) << 16);
          *(uint2*)((char*)Ps + pbase + ((g << 3) ^ sw2)) = t0;
          *(uint2*)((char*)Ps + pbase + ((32 + (g << 3)) ^ sw2)) = t1;
        }
      }
      #pragma unroll
      for (int i = 0; i < 4; i++) {
        float fi = __shfl(corr, (g << 2) + i);
        oA[0][i] *= fi; oA[1][i] *= fi; oA[2][i] *= fi; oA[3][i] *= fi;
      }
      {
        int sw2 = (ln & 3) << 4;
        #pragma unroll
        for (int hh = 0; hh < 2; hh++) {
          bf16x8 pf = *(const bf16x8*)((const char*)Ps + w * 2048 + hh * 1024 +
                                       ln * 64 + ((g << 4) ^ sw2));
          #pragma unroll
          for (int n = 0; n < 4; n++) {
            int d = n * 16 + ln;
            int vby = (d * 1024 + (kb + 32 * hh + (g << 3)) * 2) ^ ((d & 7) << 4);
            bf16x8 vf = *(const bf16x8*)((const char*)Vt + vby);
            oA[n] = __builtin_amdgcn_mfma_f32_16x16x32_bf16(pf, vf, oA[n], 0, 0, 0);
          }
        }
      }
    }
    float inv = 1.f / lrun;
    #pragma unroll
    for (int i = 0; i < 4; i++) {
      float fi = __shfl(inv, (g << 2) + i);
      int qr = q0 + (g << 2) + i;
      size_t orow = ((size_t)b * 512 + qr) * 1024 + h * 64;
      #pragma unroll
      for (int n = 0; n < 4; n++)
        o[orow + n * 16 + ln] = f2bf(oA[n][i] * fi);
    }
  }
}

// ---------------- host ----------------
extern "C" void kernel_launch(void* const* d_in, const int* in_sizes, int n_in,
                              void* d_out, int out_size, void* d_ws, size_t ws_size,
                              hipStream_t stream) {
  const float* z    = (const float*)d_in[0];
  const float* a    = (const float*)d_in[1];
  const float* te   = (const float*)d_in[2];
  const float* ipw  = (const float*)d_in[3];
  const float* ipb  = (const float*)d_in[4];
  const float* pos  = (const float*)d_in[5];
  const float* ln1w = (const float*)d_in[6];
  const float* ln1b = (const float*)d_in[7];
  const float* qkvw = (const float*)d_in[8];
  const float* projw= (const float*)d_in[9];
  const float* projb= (const float*)d_in[10];
  const float* ln2w = (const float*)d_in[11];
  const float* ln2b = (const float*)d_in[12];
  const float* w1   = (const float*)d_in[13];
  const float* b1   = (const float*)d_in[14];
  const float* w2   = (const float*)d_in[15];
  const float* b2   = (const float*)d_in[16];
  const float* onw  = (const float*)d_in[17];
  const float* onb  = (const float*)d_in[18];
  const float* dw   = (const float*)d_in[19];
  const float* db   = (const float*)d_in[20];
  float* out = (float*)d_out;

  char* p = (char*)d_ws;
  auto alloc = [&](size_t bytes) -> char* {
    char* r = p; p += (bytes + 255) & ~(size_t)255; return r;
  };
  u16* wt_in   = (u16*)alloc((size_t)1024 * 704 * 2);
  u16* wt_qkv  = (u16*)alloc((size_t)4 * 3072 * 1024 * 2);
  u16* wt_proj = (u16*)alloc((size_t)4 * 1024 * 1024 * 2);
  u16* wt_m1   = (u16*)alloc((size_t)4 * 4096 * 1024 * 2);
  u16* wt_m2   = (u16*)alloc((size_t)4 * 1024 * 4096 * 2);
  u16* wt_d    = (u16*)alloc((size_t)512 * 1024 * 2);
  u16* abuf    = (u16*)alloc((size_t)8192 * 704 * 2);
  float* xbuf  = (float*)alloc((size_t)8192 * 1024 * 4);
  u16* hbuf    = (u16*)alloc((size_t)8192 * 1024 * 2);
  u16* big     = (u16*)alloc((size_t)8192 * 4096 * 2);
  u16* obuf    = (u16*)alloc((size_t)8192 * 1024 * 2);
  u16* qkvb = big;
  u16* mid  = big;

  dim3 tb(32, 8);
  transpose_w<<<dim3(32, 22, 1), tb, 0, stream>>>(ipw, wt_in, 672, 1024, 704, 0, 0);
  transpose_w<<<dim3(96, 32, 4), tb, 0, stream>>>(qkvw, wt_qkv, 1024, 3072, 1024,
      (size_t)1024 * 3072, (size_t)3072 * 1024);
  transpose_w<<<dim3(32, 32, 4), tb, 0, stream>>>(projw, wt_proj, 1024, 1024, 1024,
      (size_t)1024 * 1024, (size_t)1024 * 1024);
  transpose_w<<<dim3(128, 32, 4), tb, 0, stream>>>(w1, wt_m1, 1024, 4096, 1024,
      (size_t)1024 * 4096, (size_t)4096 * 1024);
  transpose_w<<<dim3(32, 128, 4), tb, 0, stream>>>(w2, wt_m2, 4096, 1024, 4096,
      (size_t)4096 * 1024, (size_t)1024 * 4096);
  transpose_w<<<dim3(16, 32, 1), tb, 0, stream>>>(dw, wt_d, 1024, 512, 1024, 0, 0);

  concat_k<<<4096, 256, 0, stream>>>(z, a, te, abuf);

  // input proj + bias + pos_emb -> x (f32); K=704 -> legacy kernel
  gemm8<4, 3><<<4 * 64, 512, 0, stream>>>(abuf, wt_in, xbuf, nullptr, ipb, nullptr, pos, 8192, 1024, 704, 4);

  for (int l = 0; l < 4; l++) {
    ln_k<<<2048, 256, 0, stream>>>(xbuf, ln1w + l * 1024, ln1b + l * 1024, hbuf);
    gemmD<16><<<768, 512, 0, stream>>>(hbuf, wt_qkv + (size_t)l * 3072 * 1024, nullptr, qkvb, nullptr, nullptr, nullptr, 8192, 3072, 1024, 12);
    attn_k<<<256, 512, 0, stream>>>(qkvb, obuf);
    gemmD<5><<<256, 512, 0, stream>>>(obuf, wt_proj + (size_t)l * 1024 * 1024, xbuf, nullptr, projb + l * 1024, xbuf, nullptr, 8192, 1024, 1024, 4);
    ln_k<<<2048, 256, 0, stream>>>(xbuf, ln2w + l * 1024, ln2b + l * 1024, hbuf);
    gemmD<25><<<1024, 512, 0, stream>>>(hbuf, wt_m1 + (size_t)l * 4096 * 1024, nullptr, mid, b1 + l * 4096, nullptr, nullptr, 8192, 4096, 1024, 16);
    gemmD<5><<<256, 512, 0, stream>>>(mid, wt_m2 + (size_t)l * 1024 * 4096, xbuf, nullptr, b2 + l * 1024, xbuf, nullptr, 8192, 1024, 4096, 4);
  }
  ln_k<<<2048, 256, 0, stream>>>(xbuf, onw, onb, hbuf);
  gemmD<5><<<128, 512, 0, stream>>>(hbuf, wt_d, out, nullptr, db, z, nullptr, 8192, 512, 1024, 2);
}

// Round 12
// 1358.164 us; speedup vs baseline: 1.0165x; 1.0165x over previous
//
#include <hip/hip_runtime.h>
#include <hip/hip_bf16.h>
#include <math.h>

typedef unsigned short u16;
typedef unsigned int u32;
typedef __attribute__((ext_vector_type(4))) float f32x4;
typedef __attribute__((ext_vector_type(8))) short bf16x8;

#define DEV static __device__ __forceinline__

DEV u16 f2bf(float f) {
  __hip_bfloat16 h = __float2bfloat16(f);
  union { __hip_bfloat16 h; u16 u; } c; c.h = h; return c.u;
}

DEV float fast_gelu(float v) {
  float u = v * (1.5957691216f + 0.0713548162f * v * v);
  return v * __builtin_amdgcn_rcpf(1.f + __expf(-u));
}

DEV void gload16(const void* g, void* l) {
  __builtin_amdgcn_global_load_lds((const __attribute__((address_space(1))) u32*)g,
                                   (__attribute__((address_space(3))) u32*)l, 16, 0, 0);
}

// ------- weight transpose: fp32 [R][C] -> bf16 [C][Rp]; gridDim.z = layer -------
__global__ void transpose_w(const float* __restrict__ src, u16* __restrict__ dst,
                            int R, int C, int Rp, size_t sstride, size_t dstride) {
  src += (size_t)blockIdx.z * sstride;
  dst += (size_t)blockIdx.z * dstride;
  __shared__ float tile[32][33];
  int tx = threadIdx.x, ty = threadIdx.y;
  int c0 = blockIdx.x * 32, r0 = blockIdx.y * 32;
  #pragma unroll
  for (int j = 0; j < 4; j++) {
    int r = r0 + ty + j * 8, c = c0 + tx;
    tile[ty + j * 8][tx] = (r < R && c < C) ? src[(size_t)r * C + c] : 0.f;
  }
  __syncthreads();
  #pragma unroll
  for (int j = 0; j < 4; j++) {
    int cc = c0 + ty + j * 8;
    int rr = r0 + tx;
    if (cc < C && rr < Rp) dst[(size_t)cc * Rp + rr] = f2bf(tile[tx][ty + j * 8]);
  }
}

// ---------------- concat [z|a|task|0pad] -> bf16 [8192][704] ----------------
__global__ void concat_k(const float* __restrict__ z, const float* __restrict__ a,
                         const float* __restrict__ te, u16* __restrict__ A) {
  const int total = 8192 * 704;
  for (int idx = blockIdx.x * 256 + threadIdx.x; idx < total; idx += gridDim.x * 256) {
    int m = idx / 704;
    int j = idx - m * 704;
    float v = 0.f;
    if (j < 512) v = z[(size_t)m * 512 + j];
    else if (j < 576) v = a[(size_t)m * 64 + (j - 512)];
    else if (j < 672) v = te[(size_t)m * 96 + (j - 576)];
    A[idx] = f2bf(v);
  }
}

// ---------------- LayerNorm: fp32 [M][1024] -> bf16 [M][1024], one wave per row ----
__global__ __launch_bounds__(256) void ln_k(const float* __restrict__ x,
                                            const float* __restrict__ w,
                                            const float* __restrict__ b,
                                            u16* __restrict__ h) {
  int row = blockIdx.x * 4 + (threadIdx.x >> 6);
  int lane = threadIdx.x & 63;
  const float4* xr = (const float4*)(x + (size_t)row * 1024);
  float4 v[4]; float s = 0.f, sq = 0.f;
  #pragma unroll
  for (int i = 0; i < 4; i++) {
    v[i] = xr[lane + i * 64];
    s += v[i].x + v[i].y + v[i].z + v[i].w;
    sq += v[i].x * v[i].x + v[i].y * v[i].y + v[i].z * v[i].z + v[i].w * v[i].w;
  }
  #pragma unroll
  for (int off = 32; off >= 1; off >>= 1) { s += __shfl_xor(s, off); sq += __shfl_xor(sq, off); }
  float mean = s * (1.f / 1024.f);
  float var = sq * (1.f / 1024.f) - mean * mean;
  float rstd = rsqrtf(var + 1e-5f);
  const float4* wv = (const float4*)w;
  const float4* bv = (const float4*)b;
  u32* hr = (u32*)(h + (size_t)row * 1024);
  #pragma unroll
  for (int i = 0; i < 4; i++) {
    int idx = lane + i * 64;
    float4 wi = wv[idx], bi = bv[idx];
    float o0 = (v[i].x - mean) * rstd * wi.x + bi.x;
    float o1 = (v[i].y - mean) * rstd * wi.y + bi.y;
    float o2 = (v[i].z - mean) * rstd * wi.z + bi.z;
    float o3 = (v[i].w - mean) * rstd * wi.w + bi.w;
    hr[idx * 2]     = (u32)f2bf(o0) | ((u32)f2bf(o1) << 16);
    hr[idx * 2 + 1] = (u32)f2bf(o2) | ((u32)f2bf(o3) << 16);
  }
}

// ---------------- legacy GEMM (used for K=704 input proj) ----------------
template <int FM, int EPI>
__global__ __launch_bounds__(512, 2) void gemm8(
    const u16* __restrict__ A, const u16* __restrict__ BT,
    float* __restrict__ outF, u16* __restrict__ outH,
    const float* __restrict__ bias, const float* __restrict__ res,
    const float* __restrict__ pos, int M, int N, int K, int gx) {
  constexpr int BM = FM * 32;
  constexpr int ABYTES = BM * 64;
  constexpr int BBYTES = 256 * 64;
  constexpr int SLICE = ABYTES + BBYTES;
  constexpr int LA = ABYTES / 8192;
  constexpr int LB = 2;
  __shared__ char lds[4 * SLICE];

  const int tid = threadIdx.x, lane = tid & 63, w = tid >> 6;
  const int wr = w >> 2, wc = w & 3;

  const int nwg = gridDim.x, orig = blockIdx.x;
  const int q = nwg >> 3, r = nwg & 7;
  const int xcd = orig & 7, loc = orig >> 3;
  const int sid = (xcd < r ? xcd * (q + 1) : r * (q + 1) + (xcd - r) * q) + loc;
  const int m0 = (sid / gx) * BM, n0 = (sid % gx) * 256;

  const char* Ag = (const char*)(A + (size_t)m0 * K);
  const char* Bg = (const char*)(BT + (size_t)n0 * K);
  const int Krow = K * 2;

  int aoff[LA], boff[LB];
  #pragma unroll
  for (int l = 0; l < LA; l++) {
    int c = l * 512 + tid, rw = c >> 2, g = (c & 3) ^ ((rw >> 1) & 3);
    aoff[l] = rw * Krow + g * 16;
  }
  #pragma unroll
  for (int l = 0; l < LB; l++) {
    int c = l * 512 + tid, rw = c >> 2, g = (c & 3) ^ ((rw >> 1) & 3);
    boff[l] = rw * Krow + g * 16;
  }
  const int ra = wr * (FM * 16) + (lane & 15);
  const int aRd = ra * 64 + (((lane >> 4) ^ ((ra >> 1) & 3)) << 4);
  const int rb = wc * 64 + (lane & 15);
  const int bRd = rb * 64 + (((lane >> 4) ^ ((rb >> 1) & 3)) << 4);

  f32x4 zero4 = {0.f, 0.f, 0.f, 0.f};
  f32x4 acc[FM][4];
  #pragma unroll
  for (int m = 0; m < FM; m++)
    #pragma unroll
    for (int n = 0; n < 4; n++) acc[m][n] = zero4;

  auto stageA = [&](int s) {
    char* Ad = lds + (s & 3) * SLICE;
    const char* src = Ag + (size_t)s * 64;
    #pragma unroll
    for (int l = 0; l < LA; l++)
      gload16(src + aoff[l], Ad + (l * 512 + w * 64) * 16);
  };
  auto stageB = [&](int s) {
    char* Bd = lds + (s & 3) * SLICE + ABYTES;
    const char* src = Bg + (size_t)s * 64;
    #pragma unroll
    for (int l = 0; l < LB; l++)
      gload16(src + boff[l], Bd + (l * 512 + w * 64) * 16);
  };

  const int NS = K >> 5;
  stageA(0); stageB(0); stageA(1); stageB(1);
  asm volatile("s_waitcnt vmcnt(3)" ::: "memory");
  __builtin_amdgcn_s_barrier();

  #pragma unroll 1
  for (int s = 0; s < NS; s++) {
    char* Ar = lds + (s & 3) * SLICE;
    char* Br = Ar + ABYTES;
    const bool pre = (s + 2 < NS);
    bf16x8 bfr[4], af[4];
    #pragma unroll
    for (int n = 0; n < 4; n++) bfr[n] = *(const bf16x8*)(Br + bRd + n * 1024);
    #pragma unroll
    for (int m = 0; m < 4; m++) af[m] = *(const bf16x8*)(Ar + aRd + m * 1024);
    if (pre) { stageA(s + 2); stageB(s + 2); }
    __builtin_amdgcn_sched_barrier(0);
    __builtin_amdgcn_s_barrier();
    asm volatile("s_waitcnt lgkmcnt(0)" ::: "memory");
    __builtin_amdgcn_sched_barrier(0);
    __builtin_amdgcn_s_setprio(1);
    #pragma unroll
    for (int m = 0; m < 4; m++)
      #pragma unroll
      for (int n = 0; n < 4; n++)
        acc[m][n] = __builtin_amdgcn_mfma_f32_16x16x32_bf16(af[m], bfr[n], acc[m][n], 0, 0, 0);
    __builtin_amdgcn_s_setprio(0);
    __builtin_amdgcn_sched_barrier(0);
    if (pre) asm volatile("s_waitcnt vmcnt(3)" ::: "memory");
    else     asm volatile("s_waitcnt vmcnt(0)" ::: "memory");
    __builtin_amdgcn_s_barrier();
  }

  #pragma unroll
  for (int m = 0; m < FM; m++) {
    #pragma unroll
    for (int i = 0; i < 4; i++) {
      int gm = m0 + wr * (FM * 16) + m * 16 + ((lane >> 4) << 2) + i;
      #pragma unroll
      for (int n = 0; n < 4; n++) {
        int gn = n0 + wc * 64 + n * 16 + (lane & 15);
        float v = acc[m][n][i];
        if (EPI & 1) v += bias[gn];
        if (EPI & 2) v += pos[(size_t)(gm & 511) * N + gn];
        if (EPI & 4) v += res[(size_t)gm * N + gn];
        if (EPI & 8) v = fast_gelu(v);
        if (EPI & 16) outH[(size_t)gm * N + gn] = f2bf(v);
        else outF[(size_t)gm * N + gn] = v;
      }
    }
  }
}

// ======= gemmD: BM=128 x BN=256, BK=32, 3-slice rotation, 72KB LDS, 2 WGs/CU ======
// Swizzle (verified-zero-conflict family, R3 gemm8): slot = g ^ ((row>>1)&3).
template <int EPI>
__global__ __launch_bounds__(512, 4) void gemmD(
    const u16* __restrict__ A, const u16* __restrict__ BT,
    float* __restrict__ outF, u16* __restrict__ outH,
    const float* __restrict__ bias, const float* __restrict__ res,
    const float* __restrict__ pos, int M, int N, int K, int gx) {
  constexpr int SLICE = 24576;
  __shared__ char lds[3 * SLICE];

  const int tid = threadIdx.x, lane = tid & 63, w = tid >> 6;
  const int wr = w >> 2, wc = w & 3;
  const int ln = lane & 15, g = lane >> 4;

  const int nwg = gridDim.x, orig = blockIdx.x;
  const int q = nwg >> 3, r = nwg & 7;
  const int xcd = orig & 7, loc = orig >> 3;
  const int sid = (xcd < r ? xcd * (q + 1) : r * (q + 1) + (xcd - r) * q) + loc;
  const int m0 = (sid / gx) * 128, n0 = (sid % gx) * 256;

  const char* Ag = (const char*)(A + (size_t)m0 * K);
  const char* Bg = (const char*)(BT + (size_t)n0 * K);
  const int K2 = K * 2;
  const int NS = K >> 5, NSm1 = NS - 1;

  // read offsets: row rr, 64B rows, phys slot = g ^ ((rr>>1)&3) = g ^ ((ln>>1)&3)
  const int slotR = (g ^ ((ln >> 1) & 3)) << 4;
  int aby[4], bby[4];
  #pragma unroll
  for (int m = 0; m < 4; m++) aby[m] = (wr * 64 + m * 16 + ln) * 64 + slotR;
  #pragma unroll
  for (int n = 0; n < 4; n++)
    bby[n] = 8192 + (wc >> 1) * 8192 + ((wc & 1) * 64 + n * 16 + ln) * 64 + slotR;

  // staging offsets (pre-swizzled source, lane-linear dest)
  const int arw = tid >> 2, asl = tid & 3;
  const int aoff = arw * K2 + ((asl ^ ((arw >> 1) & 3)) << 4);
  const int brw1 = 128 + (tid >> 2);
  const int boff0 = aoff;
  const int boff1 = brw1 * K2 + ((asl ^ ((brw1 >> 1) & 3)) << 4);

  auto stage = [&](int sl3, int tau) {
    int tt = tau < NS ? tau : NSm1;
    char* base = lds + sl3 * SLICE;
    const char* sa = Ag + (size_t)tt * 64;
    const char* sb = Bg + (size_t)tt * 64;
    gload16(sa + aoff, base + tid * 16);
    gload16(sb + boff0, base + 8192 + tid * 16);
    gload16(sb + boff1, base + 8192 + (512 + tid) * 16);
  };

  f32x4 zero4 = {0.f, 0.f, 0.f, 0.f};
  f32x4 acc[4][4];
  #pragma unroll
  for (int m = 0; m < 4; m++)
    #pragma unroll
    for (int n = 0; n < 4; n++) acc[m][n] = zero4;

  bf16x8 afr[4], bfr[4];

  stage(0, 0); stage(1, 1);
  asm volatile("s_waitcnt vmcnt(3)" ::: "memory");
  __builtin_amdgcn_s_barrier();

  int s0 = 0, s1 = 1, s2 = 2;
  #pragma unroll 1
  for (int s = 0; s < NS; s++) {
    const char* base = lds + s0 * SLICE;
    stage(s2, s + 2);
    #pragma unroll
    for (int n = 0; n < 4; n++) bfr[n] = *(const bf16x8*)(base + bby[n]);
    #pragma unroll
    for (int m = 0; m < 4; m++) afr[m] = *(const bf16x8*)(base + aby[m]);
    __builtin_amdgcn_sched_barrier(0);
    asm volatile("s_waitcnt lgkmcnt(0)" ::: "memory");
    __builtin_amdgcn_sched_barrier(0);
    __builtin_amdgcn_s_setprio(1);
    #pragma unroll
    for (int m = 0; m < 4; m++)
      #pragma unroll
      for (int n = 0; n < 4; n++)
        acc[m][n] = __builtin_amdgcn_mfma_f32_16x16x32_bf16(afr[m], bfr[n], acc[m][n], 0, 0, 0);
    __builtin_amdgcn_s_setprio(0);
    __builtin_amdgcn_sched_barrier(0);
    asm volatile("s_waitcnt vmcnt(3)" ::: "memory");
    __builtin_amdgcn_s_barrier();
    int t = s0; s0 = s1; s1 = s2; s2 = t;
  }

  #pragma unroll
  for (int m = 0; m < 4; m++) {
    #pragma unroll
    for (int i = 0; i < 4; i++) {
      int gm = m0 + wr * 64 + m * 16 + (g << 2) + i;
      #pragma unroll
      for (int n = 0; n < 4; n++) {
        int gn = n0 + wc * 64 + n * 16 + ln;
        float v = acc[m][n][i];
        if (EPI & 1) v += bias[gn];
        if (EPI & 2) v += pos[(size_t)(gm & 511) * N + gn];
        if (EPI & 4) v += res[(size_t)gm * N + gn];
        if (EPI & 8) v = fast_gelu(v);
        if (EPI & 16) outH[(size_t)gm * N + gn] = f2bf(v);
        else outF[(size_t)gm * N + gn] = v;
      }
    }
  }
}

// -------- fused causal attention, one WG per (b,h), 8 waves, KVBLK=64 --------
__global__ __launch_bounds__(512) void attn_k(const u16* __restrict__ qkv,
                                              u16* __restrict__ o) {
  __shared__ u16 Ks[512 * 64];
  __shared__ u16 Vt[64 * 512];
  __shared__ u16 Ps[8 * 1024];
  const int tid = threadIdx.x, lane = tid & 63, w = tid >> 6;
  const int b = blockIdx.x >> 4, h = blockIdx.x & 15;
  const u16* base = qkv + (size_t)b * 512 * 3072 + h * 64;
  const int ln = lane & 15, g = lane >> 4;

  #pragma unroll
  for (int it = 0; it < 8; it++) {
    int chunk = it * 512 + tid;
    int row = chunk >> 3;
    int ib = (chunk & 7) * 16;
    int lb = ib ^ ((row & 7) << 4);
    gload16((const char*)(base + 1024 + (size_t)row * 3072) + lb,
            (char*)Ks + (it * 512 + w * 64) * 16);
  }
  {
    const u16* vrow = base + 2048 + (size_t)tid * 3072;
    #pragma unroll
    for (int c = 0; c < 8; c++) {
      uint4 u = *(const uint4*)(vrow + c * 8);
      u32 vals[4] = {u.x, u.y, u.z, u.w};
      #pragma unroll
      for (int pc = 0; pc < 4; pc++) {
        int d0 = c * 8 + pc * 2;
        size_t by0 = ((size_t)d0 * 1024 + tid * 2) ^ (size_t)((d0 & 7) << 4);
        size_t by1 = ((size_t)(d0 + 1) * 1024 + tid * 2) ^ (size_t)(((d0 + 1) & 7) << 4);
        *(u16*)((char*)Vt + by0) = (u16)(vals[pc] & 0xffff);
        *(u16*)((char*)Vt + by1) = (u16)(vals[pc] >> 16);
      }
    }
  }
  __syncthreads();

  const int qts[4] = {w, 15 - w, 16 + w, 31 - w};
  #pragma unroll
  for (int qi = 0; qi < 4; qi++) {
    const int qt = qts[qi];
    const int q0 = qt * 16;
    const int qcol = q0 + ln;
    const u16* qrow = base + (size_t)(q0 + ln) * 3072 + (g << 3);
    bf16x8 qf0 = *(const bf16x8*)qrow;
    bf16x8 qf1 = *(const bf16x8*)(qrow + 32);
    f32x4 zero4 = {0.f, 0.f, 0.f, 0.f};
    f32x4 oA[4] = {zero4, zero4, zero4, zero4};
    float mrun = -INFINITY, lrun = 0.f;
    const int nch = (qt >> 2) + 1;
    for (int ch = 0; ch < nch; ch++) {
      const int kb = ch * 64;
      f32x4 st[4];
      #pragma unroll
      for (int s = 0; s < 4; s++) {
        st[s] = zero4;
        int krow = kb + s * 16 + ln;
        int byc = krow * 128 + (g << 4);
        int sw = (krow & 7) << 4;
        bf16x8 ka  = *(const bf16x8*)((const char*)Ks + (byc ^ sw));
        bf16x8 kb2 = *(const bf16x8*)((const char*)Ks + ((byc + 64) ^ sw));
        st[s] = __builtin_amdgcn_mfma_f32_16x16x32_bf16(ka, qf0, st[s], 0, 0, 0);
        st[s] = __builtin_amdgcn_mfma_f32_16x16x32_bf16(kb2, qf1, st[s], 0, 0, 0);
      }
      float sv[16]; float cmax = -INFINITY;
      #pragma unroll
      for (int s = 0; s < 4; s++) {
        #pragma unroll
        for (int i = 0; i < 4; i++) {
          int key0 = kb + s * 16 + (g << 2) + i;
          float v = st[s][i] * 0.125f;
          if (key0 > qcol) v = -INFINITY;
          sv[s * 4 + i] = v;
          cmax = fmaxf(cmax, v);
        }
      }
      cmax = fmaxf(cmax, __shfl_xor(cmax, 16));
      cmax = fmaxf(cmax, __shfl_xor(cmax, 32));
      float mnew = fmaxf(mrun, cmax);
      float corr = __expf(mrun - mnew);
      float pp[16]; float psum = 0.f;
      #pragma unroll
      for (int i = 0; i < 16; i++) { pp[i] = __expf(sv[i] - mnew); psum += pp[i]; }
      psum += __shfl_xor(psum, 16);
      psum += __shfl_xor(psum, 32);
      lrun = lrun * corr + psum;
      mrun = mnew;
      {
        int sw2 = (ln & 3) << 4;
        #pragma unroll
        for (int hh = 0; hh < 2; hh++) {
          int pbase = w * 2048 + hh * 1024 + ln * 64;
          uint2 t0, t1;
          t0.x = (u32)f2bf(pp[8 * hh + 0]) | ((u32)f2bf(pp[8 * hh + 1]) << 16);
          t0.y = (u32)f2bf(pp[8 * hh + 2]) | ((u32)f2bf(pp[8 * hh + 3]) << 16);
          t1.x = (u32)f2bf(pp[8 * hh + 4]) | ((u32)f2bf(pp[8 * hh + 5]) << 16);
          t1.y = (u32)f2bf(pp[8 * hh + 6]) | ((u32)f2bf(pp[8 * hh + 7]) << 16);
          *(uint2*)((char*)Ps + pbase + ((g << 3) ^ sw2)) = t0;
          *(uint2*)((char*)Ps + pbase + ((32 + (g << 3)) ^ sw2)) = t1;
        }
      }
      #pragma unroll
      for (int i = 0; i < 4; i++) {
        float fi = __shfl(corr, (g << 2) + i);
        oA[0][i] *= fi; oA[1][i] *= fi; oA[2][i] *= fi; oA[3][i] *= fi;
      }
      {
        int sw2 = (ln & 3) << 4;
        #pragma unroll
        for (int hh = 0; hh < 2; hh++) {
          bf16x8 pf = *(const bf16x8*)((const char*)Ps + w * 2048 + hh * 1024 +
                                       ln * 64 + ((g << 4) ^ sw2));
          #pragma unroll
          for (int n = 0; n < 4; n++) {
            int d = n * 16 + ln;
            int vby = (d * 1024 + (kb + 32 * hh + (g << 3)) * 2) ^ ((d & 7) << 4);
            bf16x8 vf = *(const bf16x8*)((const char*)Vt + vby);
            oA[n] = __builtin_amdgcn_mfma_f32_16x16x32_bf16(pf, vf, oA[n], 0, 0, 0);
          }
        }
      }
    }
    float inv = 1.f / lrun;
    #pragma unroll
    for (int i = 0; i < 4; i++) {
      float fi = __shfl(inv, (g << 2) + i);
      int qr = q0 + (g << 2) + i;
      size_t orow = ((size_t)b * 512 + qr) * 1024 + h * 64;
      #pragma unroll
      for (int n = 0; n < 4; n++)
        o[orow + n * 16 + ln] = f2bf(oA[n][i] * fi);
    }
  }
}

// ---------------- host ----------------
extern "C" void kernel_launch(void* const* d_in, const int* in_sizes, int n_in,
                              void* d_out, int out_size, void* d_ws, size_t ws_size,
                              hipStream_t stream) {
  const float* z    = (const float*)d_in[0];
  const float* a    = (const float*)d_in[1];
  const float* te   = (const float*)d_in[2];
  const float* ipw  = (const float*)d_in[3];
  const float* ipb  = (const float*)d_in[4];
  const float* pos  = (const float*)d_in[5];
  const float* ln1w = (const float*)d_in[6];
  const float* ln1b = (const float*)d_in[7];
  const float* qkvw = (const float*)d_in[8];
  const float* projw= (const float*)d_in[9];
  const float* projb= (const float*)d_in[10];
  const float* ln2w = (const float*)d_in[11];
  const float* ln2b = (const float*)d_in[12];
  const float* w1   = (const float*)d_in[13];
  const float* b1   = (const float*)d_in[14];
  const float* w2   = (const float*)d_in[15];
  const float* b2   = (const float*)d_in[16];
  const float* onw  = (const float*)d_in[17];
  const float* onb  = (const float*)d_in[18];
  const float* dw   = (const float*)d_in[19];
  const float* db   = (const float*)d_in[20];
  float* out = (float*)d_out;

  char* p = (char*)d_ws;
  auto alloc = [&](size_t bytes) -> char* {
    char* r = p; p += (bytes + 255) & ~(size_t)255; return r;
  };
  u16* wt_in   = (u16*)alloc((size_t)1024 * 704 * 2);
  u16* wt_qkv  = (u16*)alloc((size_t)4 * 3072 * 1024 * 2);
  u16* wt_proj = (u16*)alloc((size_t)4 * 1024 * 1024 * 2);
  u16* wt_m1   = (u16*)alloc((size_t)4 * 4096 * 1024 * 2);
  u16* wt_m2   = (u16*)alloc((size_t)4 * 1024 * 4096 * 2);
  u16* wt_d    = (u16*)alloc((size_t)512 * 1024 * 2);
  u16* abuf    = (u16*)alloc((size_t)8192 * 704 * 2);
  float* xbuf  = (float*)alloc((size_t)8192 * 1024 * 4);
  u16* hbuf    = (u16*)alloc((size_t)8192 * 1024 * 2);
  u16* big     = (u16*)alloc((size_t)8192 * 4096 * 2);
  u16* obuf    = (u16*)alloc((size_t)8192 * 1024 * 2);
  u16* qkvb = big;
  u16* mid  = big;

  dim3 tb(32, 8);
  transpose_w<<<dim3(32, 22, 1), tb, 0, stream>>>(ipw, wt_in, 672, 1024, 704, 0, 0);
  transpose_w<<<dim3(96, 32, 4), tb, 0, stream>>>(qkvw, wt_qkv, 1024, 3072, 1024,
      (size_t)1024 * 3072, (size_t)3072 * 1024);
  transpose_w<<<dim3(32, 32, 4), tb, 0, stream>>>(projw, wt_proj, 1024, 1024, 1024,
      (size_t)1024 * 1024, (size_t)1024 * 1024);
  transpose_w<<<dim3(128, 32, 4), tb, 0, stream>>>(w1, wt_m1, 1024, 4096, 1024,
      (size_t)1024 * 4096, (size_t)4096 * 1024);
  transpose_w<<<dim3(32, 128, 4), tb, 0, stream>>>(w2, wt_m2, 4096, 1024, 4096,
      (size_t)4096 * 1024, (size_t)1024 * 4096);
  transpose_w<<<dim3(16, 32, 1), tb, 0, stream>>>(dw, wt_d, 1024, 512, 1024, 0, 0);

  concat_k<<<4096, 256, 0, stream>>>(z, a, te, abuf);

  // input proj + bias + pos_emb -> x (f32); K=704 -> legacy kernel
  gemm8<4, 3><<<4 * 64, 512, 0, stream>>>(abuf, wt_in, xbuf, nullptr, ipb, nullptr, pos, 8192, 1024, 704, 4);

  for (int l = 0; l < 4; l++) {
    ln_k<<<2048, 256, 0, stream>>>(xbuf, ln1w + l * 1024, ln1b + l * 1024, hbuf);
    gemmD<16><<<768, 512, 0, stream>>>(hbuf, wt_qkv + (size_t)l * 3072 * 1024, nullptr, qkvb, nullptr, nullptr, nullptr, 8192, 3072, 1024, 12);
    attn_k<<<256, 512, 0, stream>>>(qkvb, obuf);
    gemmD<5><<<256, 512, 0, stream>>>(obuf, wt_proj + (size_t)l * 1024 * 1024, xbuf, nullptr, projb + l * 1024, xbuf, nullptr, 8192, 1024, 1024, 4);
    ln_k<<<2048, 256, 0, stream>>>(xbuf, ln2w + l * 1024, ln2b + l * 1024, hbuf);
    gemmD<25><<<1024, 512, 0, stream>>>(hbuf, wt_m1 + (size_t)l * 4096 * 1024, nullptr, mid, b1 + l * 4096, nullptr, nullptr, 8192, 4096, 1024, 16);
    gemmD<5><<<256, 512, 0, stream>>>(mid, wt_m2 + (size_t)l * 1024 * 4096, xbuf, nullptr, b2 + l * 1024, xbuf, nullptr, 8192, 1024, 4096, 4);
  }
  ln_k<<<2048, 256, 0, stream>>>(xbuf, onw, onb, hbuf);
  gemmD<5><<<128, 512, 0, stream>>>(hbuf, wt_d, out, nullptr, db, z, nullptr, 8192, 512, 1024, 2);
}

// Round 13
// 1270.937 us; speedup vs baseline: 1.0863x; 1.0686x over previous
//
#include <hip/hip_runtime.h>
#include <hip/hip_bf16.h>
#include <math.h>

typedef unsigned short u16;
typedef unsigned int u32;
typedef __attribute__((ext_vector_type(4))) float f32x4;
typedef __attribute__((ext_vector_type(8))) short bf16x8;

#define DEV static __device__ __forceinline__

DEV u16 f2bf(float f) {
  __hip_bfloat16 h = __float2bfloat16(f);
  union { __hip_bfloat16 h; u16 u; } c; c.h = h; return c.u;
}

DEV float bf2f(u16 u) { return __uint_as_float((u32)u << 16); }

DEV float fast_gelu(float v) {
  float u = v * (1.5957691216f + 0.0713548162f * v * v);
  return v * __builtin_amdgcn_rcpf(1.f + __expf(-u));
}

DEV void gload16(const void* g, void* l) {
  __builtin_amdgcn_global_load_lds((const __attribute__((address_space(1))) u32*)g,
                                   (__attribute__((address_space(3))) u32*)l, 16, 0, 0);
}

// ------- weight transpose: fp32 [R][C] -> bf16 [C][Rp]; gridDim.z = layer -------
__global__ void transpose_w(const float* __restrict__ src, u16* __restrict__ dst,
                            int R, int C, int Rp, size_t sstride, size_t dstride) {
  src += (size_t)blockIdx.z * sstride;
  dst += (size_t)blockIdx.z * dstride;
  __shared__ float tile[32][33];
  int tx = threadIdx.x, ty = threadIdx.y;
  int c0 = blockIdx.x * 32, r0 = blockIdx.y * 32;
  #pragma unroll
  for (int j = 0; j < 4; j++) {
    int r = r0 + ty + j * 8, c = c0 + tx;
    tile[ty + j * 8][tx] = (r < R && c < C) ? src[(size_t)r * C + c] : 0.f;
  }
  __syncthreads();
  #pragma unroll
  for (int j = 0; j < 4; j++) {
    int cc = c0 + ty + j * 8;
    int rr = r0 + tx;
    if (cc < C && rr < Rp) dst[(size_t)cc * Rp + rr] = f2bf(tile[tx][ty + j * 8]);
  }
}

// ---------------- concat [z|a|task|0pad] -> bf16 [8192][704] ----------------
__global__ void concat_k(const float* __restrict__ z, const float* __restrict__ a,
                         const float* __restrict__ te, u16* __restrict__ A) {
  const int total = 8192 * 704;
  for (int idx = blockIdx.x * 256 + threadIdx.x; idx < total; idx += gridDim.x * 256) {
    int m = idx / 704;
    int j = idx - m * 704;
    float v = 0.f;
    if (j < 512) v = z[(size_t)m * 512 + j];
    else if (j < 576) v = a[(size_t)m * 64 + (j - 512)];
    else if (j < 672) v = te[(size_t)m * 96 + (j - 576)];
    A[idx] = f2bf(v);
  }
}

// ------- LayerNorm: bf16 [M][1024] -> bf16 [M][1024], one wave per row -------
__global__ __launch_bounds__(256) void ln_k(const u16* __restrict__ x,
                                            const float* __restrict__ w,
                                            const float* __restrict__ b,
                                            u16* __restrict__ h) {
  int row = blockIdx.x * 4 + (threadIdx.x >> 6);
  int lane = threadIdx.x & 63;
  const uint4* xr = (const uint4*)(x + (size_t)row * 1024);
  float f[2][8];
  float s = 0.f, sq = 0.f;
  #pragma unroll
  for (int i = 0; i < 2; i++) {
    uint4 v = xr[lane + i * 64];
    u32 wds[4] = {v.x, v.y, v.z, v.w};
    #pragma unroll
    for (int j = 0; j < 4; j++) {
      float lo = __uint_as_float(wds[j] << 16);
      float hi = __uint_as_float(wds[j] & 0xffff0000u);
      f[i][2 * j] = lo; f[i][2 * j + 1] = hi;
      s += lo + hi; sq += lo * lo + hi * hi;
    }
  }
  #pragma unroll
  for (int off = 32; off >= 1; off >>= 1) { s += __shfl_xor(s, off); sq += __shfl_xor(sq, off); }
  float mean = s * (1.f / 1024.f);
  float var = sq * (1.f / 1024.f) - mean * mean;
  float rstd = rsqrtf(var + 1e-5f);
  u32* hr = (u32*)(h + (size_t)row * 1024);
  const float2* w2 = (const float2*)w;
  const float2* b2 = (const float2*)b;
  #pragma unroll
  for (int i = 0; i < 2; i++) {
    #pragma unroll
    for (int j = 0; j < 4; j++) {
      int u = (lane + i * 64) * 4 + j;
      float2 wp = w2[u], bp = b2[u];
      float o0 = (f[i][2 * j] - mean) * rstd * wp.x + bp.x;
      float o1 = (f[i][2 * j + 1] - mean) * rstd * wp.y + bp.y;
      hr[u] = (u32)f2bf(o0) | ((u32)f2bf(o1) << 16);
    }
  }
}

// ---------------- legacy GEMM (used for K=704 input proj) ----------------
// EPI: 1=bias, 2=+pos, 4=+res f32, 8=gelu, 16=write bf16, 32=+res bf16
template <int FM, int EPI>
__global__ __launch_bounds__(512, 2) void gemm8(
    const u16* __restrict__ A, const u16* __restrict__ BT,
    float* __restrict__ outF, u16* __restrict__ outH,
    const float* __restrict__ bias, const float* __restrict__ res,
    const u16* __restrict__ resH, const float* __restrict__ pos,
    int M, int N, int K, int gx) {
  constexpr int BM = FM * 32;
  constexpr int ABYTES = BM * 64;
  constexpr int BBYTES = 256 * 64;
  constexpr int SLICE = ABYTES + BBYTES;
  constexpr int LA = ABYTES / 8192;
  constexpr int LB = 2;
  __shared__ char lds[4 * SLICE];

  const int tid = threadIdx.x, lane = tid & 63, w = tid >> 6;
  const int wr = w >> 2, wc = w & 3;

  const int nwg = gridDim.x, orig = blockIdx.x;
  const int q = nwg >> 3, r = nwg & 7;
  const int xcd = orig & 7, loc = orig >> 3;
  const int sid = (xcd < r ? xcd * (q + 1) : r * (q + 1) + (xcd - r) * q) + loc;
  const int m0 = (sid / gx) * BM, n0 = (sid % gx) * 256;

  const char* Ag = (const char*)(A + (size_t)m0 * K);
  const char* Bg = (const char*)(BT + (size_t)n0 * K);
  const int Krow = K * 2;

  int aoff[LA], boff[LB];
  #pragma unroll
  for (int l = 0; l < LA; l++) {
    int c = l * 512 + tid, rw = c >> 2, g = (c & 3) ^ ((rw >> 1) & 3);
    aoff[l] = rw * Krow + g * 16;
  }
  #pragma unroll
  for (int l = 0; l < LB; l++) {
    int c = l * 512 + tid, rw = c >> 2, g = (c & 3) ^ ((rw >> 1) & 3);
    boff[l] = rw * Krow + g * 16;
  }
  const int ra = wr * (FM * 16) + (lane & 15);
  const int aRd = ra * 64 + (((lane >> 4) ^ ((ra >> 1) & 3)) << 4);
  const int rb = wc * 64 + (lane & 15);
  const int bRd = rb * 64 + (((lane >> 4) ^ ((rb >> 1) & 3)) << 4);

  f32x4 zero4 = {0.f, 0.f, 0.f, 0.f};
  f32x4 acc[FM][4];
  #pragma unroll
  for (int m = 0; m < FM; m++)
    #pragma unroll
    for (int n = 0; n < 4; n++) acc[m][n] = zero4;

  auto stageA = [&](int s) {
    char* Ad = lds + (s & 3) * SLICE;
    const char* src = Ag + (size_t)s * 64;
    #pragma unroll
    for (int l = 0; l < LA; l++)
      gload16(src + aoff[l], Ad + (l * 512 + w * 64) * 16);
  };
  auto stageB = [&](int s) {
    char* Bd = lds + (s & 3) * SLICE + ABYTES;
    const char* src = Bg + (size_t)s * 64;
    #pragma unroll
    for (int l = 0; l < LB; l++)
      gload16(src + boff[l], Bd + (l * 512 + w * 64) * 16);
  };

  const int NS = K >> 5;
  stageA(0); stageB(0); stageA(1); stageB(1);
  asm volatile("s_waitcnt vmcnt(3)" ::: "memory");
  __builtin_amdgcn_s_barrier();

  #pragma unroll 1
  for (int s = 0; s < NS; s++) {
    char* Ar = lds + (s & 3) * SLICE;
    char* Br = Ar + ABYTES;
    const bool pre = (s + 2 < NS);
    bf16x8 bfr[4], af[4];
    #pragma unroll
    for (int n = 0; n < 4; n++) bfr[n] = *(const bf16x8*)(Br + bRd + n * 1024);
    #pragma unroll
    for (int m = 0; m < 4; m++) af[m] = *(const bf16x8*)(Ar + aRd + m * 1024);
    if (pre) { stageA(s + 2); stageB(s + 2); }
    __builtin_amdgcn_sched_barrier(0);
    __builtin_amdgcn_s_barrier();
    asm volatile("s_waitcnt lgkmcnt(0)" ::: "memory");
    __builtin_amdgcn_sched_barrier(0);
    __builtin_amdgcn_s_setprio(1);
    #pragma unroll
    for (int m = 0; m < 4; m++)
      #pragma unroll
      for (int n = 0; n < 4; n++)
        acc[m][n] = __builtin_amdgcn_mfma_f32_16x16x32_bf16(af[m], bfr[n], acc[m][n], 0, 0, 0);
    __builtin_amdgcn_s_setprio(0);
    __builtin_amdgcn_sched_barrier(0);
    if (pre) asm volatile("s_waitcnt vmcnt(3)" ::: "memory");
    else     asm volatile("s_waitcnt vmcnt(0)" ::: "memory");
    __builtin_amdgcn_s_barrier();
  }

  #pragma unroll
  for (int m = 0; m < FM; m++) {
    #pragma unroll
    for (int i = 0; i < 4; i++) {
      int gm = m0 + wr * (FM * 16) + m * 16 + ((lane >> 4) << 2) + i;
      #pragma unroll
      for (int n = 0; n < 4; n++) {
        int gn = n0 + wc * 64 + n * 16 + (lane & 15);
        float v = acc[m][n][i];
        if (EPI & 1) v += bias[gn];
        if (EPI & 2) v += pos[(size_t)(gm & 511) * N + gn];
        if (EPI & 4) v += res[(size_t)gm * N + gn];
        if (EPI & 32) v += bf2f(resH[(size_t)gm * N + gn]);
        if (EPI & 8) v = fast_gelu(v);
        if (EPI & 16) outH[(size_t)gm * N + gn] = f2bf(v);
        else outF[(size_t)gm * N + gn] = v;
      }
    }
  }
}

// ======= phase-pipelined GEMM (R7/R10 config — best measured) ======
#define SB0 __builtin_amdgcn_sched_barrier(0)
#define VMW(N) asm volatile("s_waitcnt vmcnt(" #N ")" ::: "memory")
#define PH_TAIL(MFMAS) \
  SB0; __builtin_amdgcn_s_barrier(); \
  asm volatile("s_waitcnt lgkmcnt(0)" ::: "memory"); SB0; \
  __builtin_amdgcn_s_setprio(1); MFMAS; __builtin_amdgcn_s_setprio(0); \
  SB0; __builtin_amdgcn_s_barrier();
#define PH_TAILV(MFMAS, NN) \
  SB0; __builtin_amdgcn_s_barrier(); \
  asm volatile("s_waitcnt lgkmcnt(0)" ::: "memory"); SB0; \
  __builtin_amdgcn_s_setprio(1); MFMAS; __builtin_amdgcn_s_setprio(0); \
  SB0; VMW(NN); __builtin_amdgcn_s_barrier();
#define MM16(MB, BF) \
  _Pragma("unroll") \
  for (int mm = 0; mm < 4; mm++) \
    _Pragma("unroll") \
    for (int nn = 0; nn < 4; nn++) \
      acc[(MB) + mm][nn] = __builtin_amdgcn_mfma_f32_16x16x32_bf16(afr[mm][0], BF[nn], acc[(MB) + mm][nn], 0, 0, 0);
#define MM32(MB) \
  _Pragma("unroll") \
  for (int kk2 = 0; kk2 < 2; kk2++) \
    _Pragma("unroll") \
    for (int mm = 0; mm < 4; mm++) \
      _Pragma("unroll") \
      for (int nn = 0; nn < 4; nn++) \
        acc[(MB) + mm][nn] = __builtin_amdgcn_mfma_f32_16x16x32_bf16( \
            afr[mm][kk2], kk2 ? bfr1[nn] : bfr0[nn], acc[(MB) + mm][nn], 0, 0, 0);
#define RD_A1(BUF, K2L, MB) { \
  const char* _b = aRdB[BUF]; \
  afr[0][0] = *(const bf16x8*)(_b + aby[(MB) + 0][K2L]); \
  afr[1][0] = *(const bf16x8*)(_b + aby[(MB) + 1][K2L]); \
  afr[2][0] = *(const bf16x8*)(_b + aby[(MB) + 2][K2L]); \
  afr[3][0] = *(const bf16x8*)(_b + aby[(MB) + 3][K2L]); }
#define RD_A8(BUF, MB) { \
  const char* _b = aRdB[BUF]; \
  afr[0][0] = *(const bf16x8*)(_b + aby[(MB) + 0][0]); \
  afr[0][1] = *(const bf16x8*)(_b + aby[(MB) + 0][1]); \
  afr[1][0] = *(const bf16x8*)(_b + aby[(MB) + 1][0]); \
  afr[1][1] = *(const bf16x8*)(_b + aby[(MB) + 1][1]); \
  afr[2][0] = *(const bf16x8*)(_b + aby[(MB) + 2][0]); \
  afr[2][1] = *(const bf16x8*)(_b + aby[(MB) + 2][1]); \
  afr[3][0] = *(const bf16x8*)(_b + aby[(MB) + 3][0]); \
  afr[3][1] = *(const bf16x8*)(_b + aby[(MB) + 3][1]); }
#define RD_BALL(BUF) { \
  const char* _b = bRdB[BUF]; \
  bfr0[0] = *(const bf16x8*)(_b + bby[0][0]); bfr1[0] = *(const bf16x8*)(_b + bby[0][1]); \
  bfr0[1] = *(const bf16x8*)(_b + bby[1][0]); bfr1[1] = *(const bf16x8*)(_b + bby[1][1]); \
  bfr0[2] = *(const bf16x8*)(_b + bby[2][0]); bfr1[2] = *(const bf16x8*)(_b + bby[2][1]); \
  bfr0[3] = *(const bf16x8*)(_b + bby[3][0]); bfr1[3] = *(const bf16x8*)(_b + bby[3][1]); }

template <int FM, int EPI>
__global__ __launch_bounds__(512, 2) void gemmP(
    const u16* __restrict__ A, const u16* __restrict__ BT,
    float* __restrict__ outF, u16* __restrict__ outH,
    const float* __restrict__ bias, const float* __restrict__ res,
    const u16* __restrict__ resH, const float* __restrict__ pos,
    int M, int N, int K, int gx) {
  constexpr int RB = 16384;
  constexpr int NAREG = (FM == 8 ? 4 : 2);
  constexpr int BOFF = NAREG * RB;
  __shared__ char lds[BOFF + 4 * RB];

  const int tid = threadIdx.x, lane = tid & 63, w = tid >> 6;
  const int wr = w >> 2, wc = w & 3;
  const int ln = lane & 15, g = lane >> 4;

  const int nwg = gridDim.x, orig = blockIdx.x;
  const int q = nwg >> 3, r = nwg & 7;
  const int xcd = orig & 7, loc = orig >> 3;
  const int sid = (xcd < r ? xcd * (q + 1) : r * (q + 1) + (xcd - r) * q) + loc;
  const int m0 = (sid / gx) * (FM * 32), n0 = (sid % gx) * 256;

  const char* Ag = (const char*)(A + (size_t)m0 * K);
  const char* Bg = (const char*)(BT + (size_t)n0 * K);
  const size_t K2 = (size_t)K * 2;
  const int NT = K >> 6, NTm1 = NT - 1, NI = NT >> 1;

  int aby[FM][2], bby[4][2];
  #pragma unroll
  for (int m = 0; m < FM; m++) {
    int rr = (FM == 8 ? 0 : wr * 64) + m * 16 + ln;
    #pragma unroll
    for (int k2 = 0; k2 < 2; k2++)
      aby[m][k2] = rr * 128 + (((k2 * 4 + g) ^ (rr & 7)) << 4);
  }
  #pragma unroll
  for (int n = 0; n < 4; n++) {
    int rr = (wc & 1) * 64 + n * 16 + ln;
    #pragma unroll
    for (int k2 = 0; k2 < 2; k2++)
      bby[n][k2] = rr * 128 + (((k2 * 4 + g) ^ (rr & 7)) << 4);
  }
  const char* aRdB[2];
  const char* bRdB[2];
  if constexpr (FM == 8) {
    aRdB[0] = lds + (0 * 2 + wr) * RB;
    aRdB[1] = lds + (1 * 2 + wr) * RB;
  } else {
    aRdB[0] = lds;
    aRdB[1] = lds + RB;
  }
  bRdB[0] = lds + BOFF + (0 * 2 + (wc >> 1)) * RB;
  bRdB[1] = lds + BOFF + (1 * 2 + (wc >> 1)) * RB;

  int soff[2], sdst[2];
  #pragma unroll
  for (int l = 0; l < 2; l++) {
    int c = l * 512 + tid, rw = c >> 3, sl = c & 7;
    soff[l] = rw * (int)K2 + ((sl ^ (rw & 7)) << 4);
    sdst[l] = (l * 512 + w * 64) * 16;
  }

  auto stA = [&](int buf, int tau, int h) {
    char* d = lds + (FM == 8 ? (buf * 2 + h) : buf) * RB;
    const char* s = Ag + (size_t)(tau < NT ? tau : NTm1) * 128 + (FM == 8 ? (size_t)h * 128 * K2 : 0);
    #pragma unroll
    for (int l = 0; l < 2; l++) gload16(s + soff[l], d + sdst[l]);
  };
  auto stB = [&](int buf, int tau, int gg) {
    char* d = lds + BOFF + (buf * 2 + gg) * RB;
    const char* s = Bg + (size_t)(tau < NT ? tau : NTm1) * 128 + (size_t)gg * 128 * K2;
    #pragma unroll
    for (int l = 0; l < 2; l++) gload16(s + soff[l], d + sdst[l]);
  };

  f32x4 zero4 = {0.f, 0.f, 0.f, 0.f};
  f32x4 acc[FM][4];
  #pragma unroll
  for (int m = 0; m < FM; m++)
    #pragma unroll
    for (int n = 0; n < 4; n++) acc[m][n] = zero4;

  bf16x8 afr[4][2], bfr0[4], bfr1[4];

  if constexpr (FM == 8) {
    stA(0, 0, 0); stA(0, 0, 1); stB(0, 0, 0); stB(0, 0, 1); stB(1, 1, 0); stB(1, 1, 1);
    VMW(4);
    __builtin_amdgcn_s_barrier();
    #pragma unroll 1
    for (int J = 0; J < NI; J++) {
      const int t = 2 * J;
      RD_BALL(0); RD_A8(0, 0); stA(1, t + 1, 0); stA(1, t + 1, 1);
      PH_TAIL(MM32(0));
      RD_A8(0, 4); stB(0, t + 2, 0); stB(0, t + 2, 1);
      PH_TAILV(MM32(4), 4);
      RD_BALL(1); RD_A8(1, 0); stA(0, t + 2, 0); stA(0, t + 2, 1);
      PH_TAIL(MM32(0));
      RD_A8(1, 4); stB(1, t + 3, 0); stB(1, t + 3, 1);
      PH_TAILV(MM32(4), 4);
    }
  } else {
    stA(0, 0, 0); stB(0, 0, 0); stB(0, 0, 1); stB(1, 1, 0); stB(1, 1, 1);
    VMW(4);
    __builtin_amdgcn_s_barrier();
    #pragma unroll 1
    for (int J = 0; J < NI; J++) {
      const int t = 2 * J;
      RD_BALL(0); RD_A1(0, 0, 0); stA(1, t + 1, 0);
      PH_TAIL(MM16(0, bfr0));
      RD_A1(0, 1, 0); stB(0, t + 2, 0);
      PH_TAILV(MM16(0, bfr1), 2);
      RD_BALL(1); RD_A1(1, 0, 0); stB(0, t + 2, 1); stA(0, t + 2, 0);
      PH_TAIL(MM16(0, bfr0));
      RD_A1(1, 1, 0); stB(1, t + 3, 0); stB(1, t + 3, 1);
      PH_TAILV(MM16(0, bfr1), 4);
    }
  }
  VMW(0);

  #pragma unroll
  for (int m = 0; m < FM; m++) {
    #pragma unroll
    for (int i = 0; i < 4; i++) {
      int gm = m0 + wr * (FM * 16) + m * 16 + (g << 2) + i;
      #pragma unroll
      for (int n = 0; n < 4; n++) {
        int gn = n0 + wc * 64 + n * 16 + ln;
        float v = acc[m][n][i];
        if (EPI & 1) v += bias[gn];
        if (EPI & 2) v += pos[(size_t)(gm & 511) * N + gn];
        if (EPI & 4) v += res[(size_t)gm * N + gn];
        if (EPI & 32) v += bf2f(resH[(size_t)gm * N + gn]);
        if (EPI & 8) v = fast_gelu(v);
        if (EPI & 16) outH[(size_t)gm * N + gn] = f2bf(v);
        else outF[(size_t)gm * N + gn] = v;
      }
    }
  }
}
#undef RD_BALL
#undef RD_A8
#undef RD_A1
#undef MM32
#undef MM16
#undef PH_TAILV
#undef PH_TAIL
#undef VMW
#undef SB0

// -------- fused causal attention, one WG per (b,h), 8 waves, KVBLK=64 --------
__global__ __launch_bounds__(512) void attn_k(const u16* __restrict__ qkv,
                                              u16* __restrict__ o) {
  __shared__ u16 Ks[512 * 64];
  __shared__ u16 Vt[64 * 512];
  __shared__ u16 Ps[8 * 1024];
  const int tid = threadIdx.x, lane = tid & 63, w = tid >> 6;
  const int b = blockIdx.x >> 4, h = blockIdx.x & 15;
  const u16* base = qkv + (size_t)b * 512 * 3072 + h * 64;
  const int ln = lane & 15, g = lane >> 4;

  #pragma unroll
  for (int it = 0; it < 8; it++) {
    int chunk = it * 512 + tid;
    int row = chunk >> 3;
    int ib = (chunk & 7) * 16;
    int lb = ib ^ ((row & 7) << 4);
    gload16((const char*)(base + 1024 + (size_t)row * 3072) + lb,
            (char*)Ks + (it * 512 + w * 64) * 16);
  }
  {
    const u16* vrow = base + 2048 + (size_t)tid * 3072;
    #pragma unroll
    for (int c = 0; c < 8; c++) {
      uint4 u = *(const uint4*)(vrow + c * 8);
      u32 vals[4] = {u.x, u.y, u.z, u.w};
      #pragma unroll
      for (int pc = 0; pc < 4; pc++) {
        int d0 = c * 8 + pc * 2;
        size_t by0 = ((size_t)d0 * 1024 + tid * 2) ^ (size_t)((d0 & 7) << 4);
        size_t by1 = ((size_t)(d0 + 1) * 1024 + tid * 2) ^ (size_t)(((d0 + 1) & 7) << 4);
        *(u16*)((char*)Vt + by0) = (u16)(vals[pc] & 0xffff);
        *(u16*)((char*)Vt + by1) = (u16)(vals[pc] >> 16);
      }
    }
  }
  __syncthreads();

  const int qts[4] = {w, 15 - w, 16 + w, 31 - w};
  #pragma unroll
  for (int qi = 0; qi < 4; qi++) {
    const int qt = qts[qi];
    const int q0 = qt * 16;
    const int qcol = q0 + ln;
    const u16* qrow = base + (size_t)(q0 + ln) * 3072 + (g << 3);
    bf16x8 qf0 = *(const bf16x8*)qrow;
    bf16x8 qf1 = *(const bf16x8*)(qrow + 32);
    f32x4 zero4 = {0.f, 0.f, 0.f, 0.f};
    f32x4 oA[4] = {zero4, zero4, zero4, zero4};
    float mrun = -INFINITY, lrun = 0.f;
    const int nch = (qt >> 2) + 1;
    for (int ch = 0; ch < nch; ch++) {
      const int kb = ch * 64;
      f32x4 st[4];
      #pragma unroll
      for (int s = 0; s < 4; s++) {
        st[s] = zero4;
        int krow = kb + s * 16 + ln;
        int byc = krow * 128 + (g << 4);
        int sw = (krow & 7) << 4;
        bf16x8 ka  = *(const bf16x8*)((const char*)Ks + (byc ^ sw));
        bf16x8 kb2 = *(const bf16x8*)((const char*)Ks + ((byc + 64) ^ sw));
        st[s] = __builtin_amdgcn_mfma_f32_16x16x32_bf16(ka, qf0, st[s], 0, 0, 0);
        st[s] = __builtin_amdgcn_mfma_f32_16x16x32_bf16(kb2, qf1, st[s], 0, 0, 0);
      }
      float sv[16]; float cmax = -INFINITY;
      #pragma unroll
      for (int s = 0; s < 4; s++) {
        #pragma unroll
        for (int i = 0; i < 4; i++) {
          int key0 = kb + s * 16 + (g << 2) + i;
          float v = st[s][i] * 0.125f;
          if (key0 > qcol) v = -INFINITY;
          sv[s * 4 + i] = v;
          cmax = fmaxf(cmax, v);
        }
      }
      cmax = fmaxf(cmax, __shfl_xor(cmax, 16));
      cmax = fmaxf(cmax, __shfl_xor(cmax, 32));
      float mnew = fmaxf(mrun, cmax);
      float corr = __expf(mrun - mnew);
      float pp[16]; float psum = 0.f;
      #pragma unroll
      for (int i = 0; i < 16; i++) { pp[i] = __expf(sv[i] - mnew); psum += pp[i]; }
      psum += __shfl_xor(psum, 16);
      psum += __shfl_xor(psum, 32);
      lrun = lrun * corr + psum;
      mrun = mnew;
      {
        int sw2 = (ln & 3) << 4;
        #pragma unroll
        for (int hh = 0; hh < 2; hh++) {
          int pbase = w * 2048 + hh * 1024 + ln * 64;
          uint2 t0, t1;
          t0.x = (u32)f2bf(pp[8 * hh + 0]) | ((u32)f2bf(pp[8 * hh + 1]) << 16);
          t0.y = (u32)f2bf(pp[8 * hh + 2]) | ((u32)f2bf(pp[8 * hh + 3]) << 16);
          t1.x = (u32)f2bf(pp[8 * hh + 4]) | ((u32)f2bf(pp[8 * hh + 5]) << 16);
          t1.y = (u32)f2bf(pp[8 * hh + 6]) | ((u32)f2bf(pp[8 * hh + 7]) << 16);
          *(uint2*)((char*)Ps + pbase + ((g << 3) ^ sw2)) = t0;
          *(uint2*)((char*)Ps + pbase + ((32 + (g << 3)) ^ sw2)) = t1;
        }
      }
      #pragma unroll
      for (int i = 0; i < 4; i++) {
        float fi = __shfl(corr, (g << 2) + i);
        oA[0][i] *= fi; oA[1][i] *= fi; oA[2][i] *= fi; oA[3][i] *= fi;
      }
      {
        int sw2 = (ln & 3) << 4;
        #pragma unroll
        for (int hh = 0; hh < 2; hh++) {
          bf16x8 pf = *(const bf16x8*)((const char*)Ps + w * 2048 + hh * 1024 +
                                       ln * 64 + ((g << 4) ^ sw2));
          #pragma unroll
          for (int n = 0; n < 4; n++) {
            int d = n * 16 + ln;
            int vby = (d * 1024 + (kb + 32 * hh + (g << 3)) * 2) ^ ((d & 7) << 4);
            bf16x8 vf = *(const bf16x8*)((const char*)Vt + vby);
            oA[n] = __builtin_amdgcn_mfma_f32_16x16x32_bf16(pf, vf, oA[n], 0, 0, 0);
          }
        }
      }
    }
    float inv = 1.f / lrun;
    #pragma unroll
    for (int i = 0; i < 4; i++) {
      float fi = __shfl(inv, (g << 2) + i);
      int qr = q0 + (g << 2) + i;
      size_t orow = ((size_t)b * 512 + qr) * 1024 + h * 64;
      #pragma unroll
      for (int n = 0; n < 4; n++)
        o[orow + n * 16 + ln] = f2bf(oA[n][i] * fi);
    }
  }
}

// ---------------- host ----------------
extern "C" void kernel_launch(void* const* d_in, const int* in_sizes, int n_in,
                              void* d_out, int out_size, void* d_ws, size_t ws_size,
                              hipStream_t stream) {
  const float* z    = (const float*)d_in[0];
  const float* a    = (const float*)d_in[1];
  const float* te   = (const float*)d_in[2];
  const float* ipw  = (const float*)d_in[3];
  const float* ipb  = (const float*)d_in[4];
  const float* pos  = (const float*)d_in[5];
  const float* ln1w = (const float*)d_in[6];
  const float* ln1b = (const float*)d_in[7];
  const float* qkvw = (const float*)d_in[8];
  const float* projw= (const float*)d_in[9];
  const float* projb= (const float*)d_in[10];
  const float* ln2w = (const float*)d_in[11];
  const float* ln2b = (const float*)d_in[12];
  const float* w1   = (const float*)d_in[13];
  const float* b1   = (const float*)d_in[14];
  const float* w2   = (const float*)d_in[15];
  const float* b2   = (const float*)d_in[16];
  const float* onw  = (const float*)d_in[17];
  const float* onb  = (const float*)d_in[18];
  const float* dw   = (const float*)d_in[19];
  const float* db   = (const float*)d_in[20];
  float* out = (float*)d_out;

  char* p = (char*)d_ws;
  auto alloc = [&](size_t bytes) -> char* {
    char* r = p; p += (bytes + 255) & ~(size_t)255; return r;
  };
  u16* wt_in   = (u16*)alloc((size_t)1024 * 704 * 2);
  u16* wt_qkv  = (u16*)alloc((size_t)4 * 3072 * 1024 * 2);
  u16* wt_proj = (u16*)alloc((size_t)4 * 1024 * 1024 * 2);
  u16* wt_m1   = (u16*)alloc((size_t)4 * 4096 * 1024 * 2);
  u16* wt_m2   = (u16*)alloc((size_t)4 * 1024 * 4096 * 2);
  u16* wt_d    = (u16*)alloc((size_t)512 * 1024 * 2);
  u16* abuf    = (u16*)alloc((size_t)8192 * 704 * 2);
  u16* xbuf    = (u16*)alloc((size_t)8192 * 1024 * 2);  // bf16 residual stream
  u16* hbuf    = (u16*)alloc((size_t)8192 * 1024 * 2);
  u16* big     = (u16*)alloc((size_t)8192 * 4096 * 2);
  u16* obuf    = (u16*)alloc((size_t)8192 * 1024 * 2);
  u16* qkvb = big;
  u16* mid  = big;

  dim3 tb(32, 8);
  transpose_w<<<dim3(32, 22, 1), tb, 0, stream>>>(ipw, wt_in, 672, 1024, 704, 0, 0);
  transpose_w<<<dim3(96, 32, 4), tb, 0, stream>>>(qkvw, wt_qkv, 1024, 3072, 1024,
      (size_t)1024 * 3072, (size_t)3072 * 1024);
  transpose_w<<<dim3(32, 32, 4), tb, 0, stream>>>(projw, wt_proj, 1024, 1024, 1024,
      (size_t)1024 * 1024, (size_t)1024 * 1024);
  transpose_w<<<dim3(128, 32, 4), tb, 0, stream>>>(w1, wt_m1, 1024, 4096, 1024,
      (size_t)1024 * 4096, (size_t)4096 * 1024);
  transpose_w<<<dim3(32, 128, 4), tb, 0, stream>>>(w2, wt_m2, 4096, 1024, 4096,
      (size_t)4096 * 1024, (size_t)1024 * 4096);
  transpose_w<<<dim3(16, 32, 1), tb, 0, stream>>>(dw, wt_d, 1024, 512, 1024, 0, 0);

  concat_k<<<4096, 256, 0, stream>>>(z, a, te, abuf);

  // input proj + bias + pos_emb -> xbuf (bf16)
  gemm8<4, 19><<<4 * 64, 512, 0, stream>>>(abuf, wt_in, nullptr, xbuf, ipb, nullptr, nullptr, pos, 8192, 1024, 704, 4);

  for (int l = 0; l < 4; l++) {
    ln_k<<<2048, 256, 0, stream>>>(xbuf, ln1w + l * 1024, ln1b + l * 1024, hbuf);
    gemmP<8, 16><<<384, 512, 0, stream>>>(hbuf, wt_qkv + (size_t)l * 3072 * 1024, nullptr, qkvb, nullptr, nullptr, nullptr, nullptr, 8192, 3072, 1024, 12);
    attn_k<<<256, 512, 0, stream>>>(qkvb, obuf);
    gemmP<4, 49><<<256, 512, 0, stream>>>(obuf, wt_proj + (size_t)l * 1024 * 1024, nullptr, xbuf, projb + l * 1024, nullptr, xbuf, nullptr, 8192, 1024, 1024, 4);
    ln_k<<<2048, 256, 0, stream>>>(xbuf, ln2w + l * 1024, ln2b + l * 1024, hbuf);
    gemmP<8, 25><<<512, 512, 0, stream>>>(hbuf, wt_m1 + (size_t)l * 4096 * 1024, nullptr, mid, b1 + l * 4096, nullptr, nullptr, nullptr, 8192, 4096, 1024, 16);
    gemmP<4, 49><<<256, 512, 0, stream>>>(mid, wt_m2 + (size_t)l * 1024 * 4096, nullptr, xbuf, b2 + l * 1024, nullptr, xbuf, nullptr, 8192, 1024, 4096, 4);
  }
  ln_k<<<2048, 256, 0, stream>>>(xbuf, onw, onb, hbuf);
  gemmP<4, 5><<<128, 512, 0, stream>>>(hbuf, wt_d, out, nullptr, db, z, nullptr, nullptr, 8192, 512, 1024, 2);
}